// Round 2
// baseline (3847.977 us; speedup 1.0000x reference)
//
#include <hip/hip_runtime.h>

// GCN-EEGNet forward, MI355X. Dtype-adaptive: K0 detects on-device whether
// float inputs are fp32 or bf16 (sentinel: adjacency[0,0] read as float is
// exactly 1.0f iff fp32). Small weights are converted to canonical fp32 in
// ws; big intermediates are bf16 in ws; output store branches on the flag.
// Pipeline: K0 setup -> K1 conv1+bn -> 3x [K2 sparse graph einsum ->
// K3 gconv+bn+elu] -> K4 dw+bn+elu+pool4 -> K5 sep(dw+pw)+bn+elu -> K6 fc.

#define B_   32
#define C_   64
#define T_   4000
#define F1_  8
#define TP_  1000
#define W2_  1001
#define MAXDEG 16

static __device__ __forceinline__ float bf2f(unsigned short h) {
  union { unsigned int u; float f; } v; v.u = ((unsigned int)h) << 16; return v.f;
}
static __device__ __forceinline__ unsigned short f2bf(float f) {
  union { float f; unsigned int u; } v; v.f = f;
  unsigned int r = v.u + 0x7FFFu + ((v.u >> 16) & 1u);
  return (unsigned short)(r >> 16);
}
static __device__ __forceinline__ float eluf(float z) {
  return z > 0.0f ? z : expm1f(z);
}
// flag-aware raw-input load
static __device__ __forceinline__ float ldin(const void* p, int i, int isf32) {
  return isf32 ? ((const float*)p)[i] : bf2f(((const unsigned short*)p)[i]);
}

// ---------------- K0: dtype detect + weight canonicalization + CSR ---------
__global__ __launch_bounds__(256) void k0_setup(
    const void* __restrict__ adj, const void* __restrict__ imp,
    const void* __restrict__ dww, const void* __restrict__ w1,
    const void* __restrict__ bnF, const void* __restrict__ gw,
    const void* __restrict__ bnsp, const void* __restrict__ sdw,
    const void* __restrict__ pw, const void* __restrict__ bnsep,
    const void* __restrict__ fcw, const void* __restrict__ fcb,
    int* __restrict__ flag, int* __restrict__ deg, int* __restrict__ col,
    float* __restrict__ avals, float* __restrict__ w1c,
    float* __restrict__ bnFc, float* __restrict__ gwc,
    float* __restrict__ dwn, float* __restrict__ bnspc,
    float* __restrict__ sdwc, float* __restrict__ pwc,
    float* __restrict__ bnsepc, float* __restrict__ fcwc,
    float* __restrict__ fcbc)
{
  __shared__ float dwr[1024];
  __shared__ float dsc[16];
  int tid = threadIdx.x;
  int isf32 = (((const float*)adj)[0] == 1.0f) ? 1 : 0;
  if (tid == 0) *flag = isf32;

  for (int i = tid; i < 512;  i += 256) w1c[i]    = ldin(w1, i, isf32);
  for (int i = tid; i < 128;  i += 256) bnFc[i]   = ldin(bnF, i, isf32);
  for (int i = tid; i < 1536; i += 256) gwc[i]    = ldin(gw, i, isf32);
  for (int i = tid; i < 64;   i += 256) bnspc[i]  = ldin(bnsp, i, isf32);
  for (int i = tid; i < 256;  i += 256) sdwc[i]   = ldin(sdw, i, isf32);
  for (int i = tid; i < 256;  i += 256) pwc[i]    = ldin(pw, i, isf32);
  for (int i = tid; i < 64;   i += 256) bnsepc[i] = ldin(bnsep, i, isf32);
  for (int i = tid; i < 8000; i += 256) fcwc[i]   = ldin(fcw, i, isf32);
  if (tid < 4) fcbc[tid] = ldin(fcb, tid, isf32);
  for (int i = tid; i < 1024; i += 256) dwr[i] = ldin(dww, i, isf32);

  if (tid < 64) {            // CSR of adjacency (data-driven, no hardcoding)
    int c = tid, n = 0;
    for (int d = 0; d < 64; ++d) {
      if (ldin(adj, c*64 + d, isf32) != 0.0f) {
        if (n < MAXDEG) col[c*MAXDEG + n] = d;
        ++n;
      }
    }
    deg[c] = n < MAXDEG ? n : MAXDEG;
  }
  __syncthreads();
  if (tid < 16) {            // dw norm clamp scale
    float s2 = 0.0f;
    for (int c2 = 0; c2 < 64; ++c2) { float wv = dwr[tid*64 + c2]; s2 += wv*wv; }
    dsc[tid] = fminf(1.0f, 1.0f / fmaxf(sqrtf(s2), 1e-7f));
  }
  for (int combo = tid; combo < 3*8*64; combo += 256) {
    int l = combo >> 9, f = (combo >> 6) & 7, c = combo & 63;
    int dg = deg[c];
    for (int e = 0; e < dg; ++e) {
      int d = col[c*MAXDEG + e];
      avals[((l*8 + f)*64 + c)*MAXDEG + e] =
          ldin(adj, c*64 + d, isf32) * ldin(imp, ((l*8 + f)*64 + c)*64 + d, isf32);
    }
  }
  __syncthreads();
  for (int i = tid; i < 1024; i += 256) dwn[i] = dwr[i] * dsc[i >> 6];
}

// ---------------- K1: conv1 (64-tap along T) + bn0 -------------------------
// grid (16 t-tiles of 256, B*C). Each thread: one t, all 8 f outputs.
__global__ __launch_bounds__(256) void k1_conv1_bn(
    const void* __restrict__ x,               // B,C,T (raw dtype)
    const float* __restrict__ w1c,            // 8x64
    const float* __restrict__ bnFc,           // 4x4x8
    const int* __restrict__ flag,
    unsigned short* __restrict__ outp)        // B,F1,C,T bf16
{
  __shared__ float xs[320];
  __shared__ float wt[512];
  __shared__ float ssc[8], ssh[8];
  int tid = threadIdx.x;
  int bc = blockIdx.y;                 // b*64+c
  int b = bc >> 6, c = bc & 63;
  int tb = blockIdx.x * 256;
  int isf32 = *flag;
  int row = bc * T_;
  for (int i = tid; i < 320; i += 256) {
    int t = tb - 31 + i;
    xs[i] = (t >= 0 && t < T_) ? ldin(x, row + t, isf32) : 0.0f;
  }
  for (int i = tid; i < 512; i += 256) wt[i] = w1c[i];
  if (tid < 8) {
    float g = bnFc[tid], bb = bnFc[8 + tid], m = bnFc[16 + tid], v = bnFc[24 + tid];
    float sc = g * rsqrtf(v + 1e-3f);
    ssc[tid] = sc; ssh[tid] = bb - m * sc;
  }
  __syncthreads();
  int t = tb + tid;
  if (t >= T_) return;
  float acc[8] = {0,0,0,0,0,0,0,0};
  #pragma unroll 4
  for (int k = 0; k < 64; ++k) {
    float v = xs[tid + k];
    #pragma unroll
    for (int f = 0; f < 8; ++f) acc[f] = fmaf(wt[f*64 + k], v, acc[f]);
  }
  #pragma unroll
  for (int f = 0; f < 8; ++f)
    outp[((b*8 + f)*64 + c)*T_ + t] = f2bf(acc[f]*ssc[f] + ssh[f]);
}

// ---------------- K2: sparse graph einsum h'[c,t] = sum_d A[f,c,d] h[d,t] --
__global__ __launch_bounds__(256) void k2_gcn(
    const unsigned short* __restrict__ in,    // B,F1,C,T bf16
    unsigned short* __restrict__ outp,        // B,F1,C,T bf16
    const int* __restrict__ deg, const int* __restrict__ col,
    const float* __restrict__ avals, int l)
{
  __shared__ unsigned short sl[64*256];
  int tid = threadIdx.x;
  int bf = blockIdx.y;                 // b*8+f
  int tb = blockIdx.x * 256;
  int base = bf * (64 * T_);
  for (int idx = tid; idx < 64*256; idx += 256) {
    int d = idx >> 8, tt = idx & 255;
    int t = tb + tt;
    sl[idx] = (t < T_) ? in[base + d*T_ + t] : (unsigned short)0;
  }
  __syncthreads();
  int t = tb + tid;
  if (t >= T_) return;
  int f = bf & 7;
  const float* av = avals + (l*8 + f) * (64 * MAXDEG);
  for (int c = 0; c < 64; ++c) {
    int dg = deg[c];
    float a = 0.0f;
    for (int e = 0; e < dg; ++e) {
      int d = col[c*MAXDEG + e];
      a = fmaf(av[c*MAXDEG + e], bf2f(sl[(d << 8) + tid]), a);
    }
    outp[base + c*T_ + t] = f2bf(a);
  }
}

// ---------------- K3: gconv (8ch x 8tap) + bn + elu ------------------------
// grid (16 t-tiles of 256, B*C). Each thread: one t, all 8 o outputs.
__global__ __launch_bounds__(256) void k3_gconv(
    const unsigned short* __restrict__ in,    // B,F1,C,T bf16 (Ah)
    const float* __restrict__ gwc,            // 3x8x8x8
    const float* __restrict__ bnFc,           // 4x4x8
    unsigned short* __restrict__ outp,        // B,F1,C,T bf16
    int l)
{
  __shared__ float xsh[8*264];
  __shared__ float wt[512];
  __shared__ float ssc[8], ssh[8];
  int tid = threadIdx.x;
  int bc = blockIdx.y;                 // b*64+c
  int b = bc >> 6, c = bc & 63;
  int tb = blockIdx.x * 256;
  for (int idx = tid; idx < 8*264; idx += 256) {
    int i = idx / 264, s = idx - i*264;
    int t = tb - 3 + s;
    xsh[idx] = (t >= 0 && t < T_) ? bf2f(in[((b*8 + i)*64 + c)*T_ + t]) : 0.0f;
  }
  for (int i = tid; i < 512; i += 256) wt[i] = gwc[l*512 + i];
  if (tid < 8) {
    float g  = bnFc[(l+1)*32 + 0*8 + tid], bb = bnFc[(l+1)*32 + 1*8 + tid];
    float m  = bnFc[(l+1)*32 + 2*8 + tid], v  = bnFc[(l+1)*32 + 3*8 + tid];
    float sc = g * rsqrtf(v + 1e-3f);
    ssc[tid] = sc; ssh[tid] = bb - m * sc;
  }
  __syncthreads();
  int t = tb + tid;
  if (t >= T_) return;
  float acc[8] = {0,0,0,0,0,0,0,0};
  #pragma unroll
  for (int i = 0; i < 8; ++i) {
    #pragma unroll
    for (int k = 0; k < 8; ++k) {
      float v = xsh[i*264 + tid + k];
      #pragma unroll
      for (int o = 0; o < 8; ++o) acc[o] = fmaf(wt[(o*8 + i)*8 + k], v, acc[o]);
    }
  }
  #pragma unroll
  for (int o = 0; o < 8; ++o) {
    float z = acc[o]*ssc[o] + ssh[o];
    outp[((b*8 + o)*64 + c)*T_ + t] = f2bf(eluf(z));
  }
}

// ---------------- K4: depthwise-over-C conv + bn + elu + avgpool4 ----------
__global__ __launch_bounds__(256) void k4_dw(
    const unsigned short* __restrict__ in,    // B,F1,C,T bf16
    const float* __restrict__ dwn,            // 16x64 (pre-clamped)
    const float* __restrict__ bnspc,          // 4x16
    float* __restrict__ p1)                   // B,16,1000 fp32
{
  __shared__ unsigned short sl[64*256];
  __shared__ float es[2][256];
  int tid = threadIdx.x;
  int bg = blockIdx.y;                 // b*8+g
  int b = bg >> 3, g = bg & 7;
  int tb = blockIdx.x * 256;
  int base = bg * (64 * T_);
  for (int idx = tid; idx < 64*256; idx += 256) {
    int cc = idx >> 8, tt = idx & 255;
    int t = tb + tt;
    sl[idx] = (t < T_) ? in[base + cc*T_ + t] : (unsigned short)0;
  }
  __syncthreads();
  float a0 = 0.0f, a1 = 0.0f;
  for (int cc = 0; cc < 64; ++cc) {
    float hv = bf2f(sl[(cc << 8) + tid]);
    a0 = fmaf(dwn[(2*g)*64 + cc],   hv, a0);
    a1 = fmaf(dwn[(2*g+1)*64 + cc], hv, a1);
  }
  #pragma unroll
  for (int j = 0; j < 2; ++j) {
    int ch = 2*g + j;
    float a = j ? a1 : a0;
    float gg = bnspc[0*16+ch], bb = bnspc[1*16+ch];
    float mm = bnspc[2*16+ch], vv = bnspc[3*16+ch];
    float sc = gg * rsqrtf(vv + 1e-3f);
    es[j][tid] = eluf(a*sc + (bb - mm*sc));
  }
  __syncthreads();
  if (tid < 128) {
    int j = tid >> 6, q = tid & 63;
    int oi = (tb >> 2) + q;
    if (oi < TP_) {
      float s = es[j][4*q] + es[j][4*q+1] + es[j][4*q+2] + es[j][4*q+3];
      p1[(b*16 + 2*g + j)*TP_ + oi] = 0.25f * s;
    }
  }
}

// ---------------- K5: sep depthwise(16tap) + pointwise(16x16) + bn + elu ---
__global__ __launch_bounds__(256) void k5_sep(
    const float* __restrict__ p1,             // B,16,1000
    const float* __restrict__ sdwc,           // 16x16
    const float* __restrict__ pwc,            // 16x16
    const float* __restrict__ bnsepc,         // 4x16
    float* __restrict__ p2)                   // B,16,1001
{
  __shared__ float ps[16*TP_];
  int tid = threadIdx.x;
  int b = blockIdx.x;
  for (int idx = tid; idx < 16*TP_; idx += 256) ps[idx] = p1[b*16*TP_ + idx];
  __syncthreads();
  for (int w0 = tid; w0 < W2_; w0 += 256) {
    float dws[16];
    for (int ch = 0; ch < 16; ++ch) {
      float a = 0.0f;
      #pragma unroll
      for (int k = 0; k < 16; ++k) {
        int mi = w0 - 8 + k;
        float v = ((unsigned)mi < (unsigned)TP_) ? ps[ch*TP_ + mi] : 0.0f;
        a = fmaf(sdwc[ch*16 + k], v, a);
      }
      dws[ch] = a;
    }
    for (int f = 0; f < 16; ++f) {
      float a = 0.0f;
      #pragma unroll
      for (int ch = 0; ch < 16; ++ch) a = fmaf(pwc[f*16 + ch], dws[ch], a);
      float gg = bnsepc[0*16+f], bb = bnsepc[1*16+f];
      float mm = bnsepc[2*16+f], vv = bnsepc[3*16+f];
      float sc = gg * rsqrtf(vv + 1e-3f);
      p2[(b*16 + f)*W2_ + w0] = eluf(a*sc + (bb - mm*sc));
    }
  }
}

// ---------------- K6: avgpool8 (first 1000) + fc (dtype-adaptive store) ----
__global__ __launch_bounds__(256) void k6_fc(
    const float* __restrict__ p2,             // B,16,1001
    const float* __restrict__ fcwc,           // 4x2000
    const float* __restrict__ fcbc,           // 4
    const int* __restrict__ flag,
    void* __restrict__ outp)                  // B,4
{
  __shared__ float red[4*256];
  int tid = threadIdx.x;
  int b = blockIdx.x;
  float part[4] = {0.0f, 0.0f, 0.0f, 0.0f};
  for (int idx = tid; idx < 2000; idx += 256) {
    int f = idx / 125, q = idx - f*125;
    const float* src = p2 + (b*16 + f)*W2_ + q*8;
    float s = src[0]+src[1]+src[2]+src[3]+src[4]+src[5]+src[6]+src[7];
    float mval = 0.125f * s;
    #pragma unroll
    for (int n = 0; n < 4; ++n) part[n] = fmaf(fcwc[n*2000 + idx], mval, part[n]);
  }
  #pragma unroll
  for (int n = 0; n < 4; ++n) red[n*256 + tid] = part[n];
  __syncthreads();
  for (int s = 128; s > 0; s >>= 1) {
    if (tid < s) {
      #pragma unroll
      for (int n = 0; n < 4; ++n) red[n*256 + tid] += red[n*256 + tid + s];
    }
    __syncthreads();
  }
  if (tid < 4) {
    float val = red[tid*256] + fcbc[tid];
    if (*flag) ((float*)outp)[b*4 + tid] = val;
    else       ((unsigned short*)outp)[b*4 + tid] = f2bf(val);
  }
}

// ---------------------------------------------------------------------------
extern "C" void kernel_launch(void* const* d_in, const int* in_sizes, int n_in,
                              void* d_out, int out_size, void* d_ws, size_t ws_size,
                              hipStream_t stream) {
  const void* x     = d_in[0];
  const void* adj   = d_in[1];
  const void* w1    = d_in[2];
  const void* bnF   = d_in[3];
  const void* imp   = d_in[4];
  const void* gw    = d_in[5];
  const void* dww   = d_in[6];
  const void* bnsp  = d_in[7];
  const void* sdw   = d_in[8];
  const void* pw    = d_in[9];
  const void* bnsep = d_in[10];
  const void* fcw   = d_in[11];
  const void* fcb   = d_in[12];

  char* w = (char*)d_ws;
  const size_t OFF = 262144000;  // after two 131,072,000-byte bf16 buffers
  unsigned short* bufA = (unsigned short*)(w);
  unsigned short* bufB = (unsigned short*)(w + 131072000);
  int*   flag   = (int*)  (w + OFF + 0);
  int*   deg    = (int*)  (w + OFF + 256);
  int*   col    = (int*)  (w + OFF + 512);
  float* avals  = (float*)(w + OFF + 4608);
  float* w1c    = (float*)(w + OFF + 102912);
  float* bnFc   = (float*)(w + OFF + 104960);
  float* gwc    = (float*)(w + OFF + 105472);
  float* dwn    = (float*)(w + OFF + 111616);
  float* bnspc  = (float*)(w + OFF + 115712);
  float* sdwc   = (float*)(w + OFF + 115968);
  float* pwc    = (float*)(w + OFF + 116992);
  float* bnsepc = (float*)(w + OFF + 118016);
  float* fcwc   = (float*)(w + OFF + 118272);
  float* fcbc   = (float*)(w + OFF + 150272);
  float* p1     = (float*)(w + OFF + 150528);
  float* p2     = (float*)(w + OFF + 2198528);

  k0_setup<<<1, 256, 0, stream>>>(adj, imp, dww, w1, bnF, gw, bnsp, sdw, pw,
                                  bnsep, fcw, fcb, flag, deg, col, avals, w1c,
                                  bnFc, gwc, dwn, bnspc, sdwc, pwc, bnsepc,
                                  fcwc, fcbc);
  k1_conv1_bn<<<dim3(16, B_*C_), 256, 0, stream>>>(x, w1c, bnFc, flag, bufA);
  for (int l = 0; l < 3; ++l) {
    k2_gcn<<<dim3(16, B_*F1_), 256, 0, stream>>>(bufA, bufB, deg, col, avals, l);
    k3_gconv<<<dim3(16, B_*C_), 256, 0, stream>>>(bufB, gwc, bnFc, bufA, l);
  }
  k4_dw<<<dim3(16, B_*F1_), 256, 0, stream>>>(bufA, dwn, bnspc, p1);
  k5_sep<<<32, 256, 0, stream>>>(p1, sdwc, pwc, bnsepc, p2);
  k6_fc<<<32, 256, 0, stream>>>(p2, fcwc, fcbc, flag, d_out);
}

// Round 4
// 1483.724 us; speedup vs baseline: 2.5935x; 2.5935x over previous
//
#include <hip/hip_runtime.h>

// GCN-EEGNet forward, MI355X. Dtype-adaptive (fp32/bf16 inputs detected in
// K0 via adjacency sentinel). Weights canonicalized to fp32 in ws and read
// by compute kernels with WAVE-UNIFORM indices -> s_load -> SGPR operands
// (round-2 lesson: LDS weight reads per-FMA blew VGPRs to 256 / 12% occ).
// Big intermediates bf16 in ws. Convs: 4 t/thread, aligned float4 LDS
// window reads, acc in regs. Round-4 fix: K1 sliding-window prefetch was
// +4 elements off (read s=4tid+16+4cc instead of 4tid+12+4cc).
// Pipeline: K0 setup -> K1 conv1+bn -> 3x [K2 sparse graph einsum ->
// K3 gconv+bn+elu] -> K4 dw+bn+elu+pool4 -> K5 sep(dw+pw)+bn+elu -> K6 fc.

#define B_   32
#define C_   64
#define T_   4000
#define F1_  8
#define TP_  1000
#define W2_  1001
#define MAXDEG 16

static __device__ __forceinline__ float bf2f(unsigned short h) {
  union { unsigned int u; float f; } v; v.u = ((unsigned int)h) << 16; return v.f;
}
static __device__ __forceinline__ float lo_f(unsigned int u) {
  union { unsigned int u; float f; } v; v.u = u << 16; return v.f;
}
static __device__ __forceinline__ float hi_f(unsigned int u) {
  union { unsigned int u; float f; } v; v.u = u & 0xFFFF0000u; return v.f;
}
static __device__ __forceinline__ unsigned short f2bf(float f) {
  union { float f; unsigned int u; } v; v.f = f;
  unsigned int r = v.u + 0x7FFFu + ((v.u >> 16) & 1u);
  return (unsigned short)(r >> 16);
}
static __device__ __forceinline__ float eluf(float z) {
  return z > 0.0f ? z : expm1f(z);
}
static __device__ __forceinline__ float ldin(const void* p, int i, int isf32) {
  return isf32 ? ((const float*)p)[i] : bf2f(((const unsigned short*)p)[i]);
}

// ---------------- K0: dtype detect + canonicalize + CSR + bn fold ----------
__global__ __launch_bounds__(256) void k0_setup(
    const void* __restrict__ adj, const void* __restrict__ imp,
    const void* __restrict__ dww, const void* __restrict__ w1,
    const void* __restrict__ bnF, const void* __restrict__ gw,
    const void* __restrict__ bnsp, const void* __restrict__ sdw,
    const void* __restrict__ pw, const void* __restrict__ bnsep,
    const void* __restrict__ fcw, const void* __restrict__ fcb,
    int* __restrict__ flag, int* __restrict__ deg, int* __restrict__ col,
    float* __restrict__ avals, float* __restrict__ w1c,
    float* __restrict__ gwc, float* __restrict__ dwn,
    float* __restrict__ sdwc, float* __restrict__ pwc,
    float* __restrict__ fcwc, float* __restrict__ fcbc,
    float* __restrict__ bnFs, float* __restrict__ bnsps,
    float* __restrict__ bnseps)
{
  __shared__ float dwr[1024];
  __shared__ float dsc[16];
  int tid = threadIdx.x;
  int isf32 = (((const float*)adj)[0] == 1.0f) ? 1 : 0;
  if (tid == 0) *flag = isf32;

  for (int i = tid; i < 512;  i += 256) w1c[i]  = ldin(w1, i, isf32);
  for (int i = tid; i < 1536; i += 256) gwc[i]  = ldin(gw, i, isf32);
  for (int i = tid; i < 256;  i += 256) sdwc[i] = ldin(sdw, i, isf32);
  for (int i = tid; i < 256;  i += 256) pwc[i]  = ldin(pw, i, isf32);
  for (int i = tid; i < 8000; i += 256) fcwc[i] = ldin(fcw, i, isf32);
  if (tid < 4) fcbc[tid] = ldin(fcb, tid, isf32);
  for (int i = tid; i < 1024; i += 256) dwr[i] = ldin(dww, i, isf32);

  if (tid < 64) {            // CSR of adjacency (data-driven)
    int c = tid, n = 0;
    for (int d = 0; d < 64; ++d) {
      if (ldin(adj, c*64 + d, isf32) != 0.0f) {
        if (n < MAXDEG) col[c*MAXDEG + n] = d;
        ++n;
      }
    }
    deg[c] = n < MAXDEG ? n : MAXDEG;
  }
  __syncthreads();
  if (tid < 16) {            // dw norm clamp scale
    float s2 = 0.0f;
    for (int c2 = 0; c2 < 64; ++c2) { float wv = dwr[tid*64 + c2]; s2 += wv*wv; }
    dsc[tid] = fminf(1.0f, 1.0f / fmaxf(sqrtf(s2), 1e-7f));
  }
  if (tid >= 64 && tid < 96) {   // bnF folded scale/shift: 4 stages x 8 ch
    int i = tid - 64, s = i >> 3, f = i & 7;
    float g = ldin(bnF, s*32 + f,      isf32);
    float b = ldin(bnF, s*32 + 8 + f,  isf32);
    float m = ldin(bnF, s*32 + 16 + f, isf32);
    float v = ldin(bnF, s*32 + 24 + f, isf32);
    float sc = g * rsqrtf(v + 1e-3f);
    bnFs[s*16 + f] = sc; bnFs[s*16 + 8 + f] = b - m*sc;
  }
  if (tid >= 96 && tid < 112) {  // bn_sp
    int ch = tid - 96;
    float g = ldin(bnsp, ch, isf32), b = ldin(bnsp, 16 + ch, isf32);
    float m = ldin(bnsp, 32 + ch, isf32), v = ldin(bnsp, 48 + ch, isf32);
    float sc = g * rsqrtf(v + 1e-3f);
    bnsps[ch] = sc; bnsps[16 + ch] = b - m*sc;
  }
  if (tid >= 112 && tid < 128) { // bn_sep
    int ch = tid - 112;
    float g = ldin(bnsep, ch, isf32), b = ldin(bnsep, 16 + ch, isf32);
    float m = ldin(bnsep, 32 + ch, isf32), v = ldin(bnsep, 48 + ch, isf32);
    float sc = g * rsqrtf(v + 1e-3f);
    bnseps[ch] = sc; bnseps[16 + ch] = b - m*sc;
  }
  for (int combo = tid; combo < 3*8*64; combo += 256) {
    int l = combo >> 9, f = (combo >> 6) & 7, c = combo & 63;
    int dg = deg[c];
    for (int e = 0; e < dg; ++e) {
      int d = col[c*MAXDEG + e];
      avals[((l*8 + f)*64 + c)*MAXDEG + e] =
          ldin(adj, c*64 + d, isf32) * ldin(imp, ((l*8 + f)*64 + c)*64 + d, isf32);
    }
  }
  __syncthreads();
  for (int i = tid; i < 1024; i += 256) dwn[i] = dwr[i] * dsc[i >> 6];
}

// ---------------- K1: conv1 (64-tap) + bn0. 4 t/thread, SGPR weights -------
// grid (4 t-tiles of 1024, B*C). Stage row from t=tb-35 so float4 reads align.
// Invariant entering chunk cc: A4 = xs[4tid+4+4cc ..], B4 = xs[4tid+8+4cc ..].
__global__ __launch_bounds__(256, 4) void k1_conv1_bn(
    const void* __restrict__ x,               // B,C,T raw dtype
    const float* __restrict__ w1c,            // 8x64 fp32 (uniform -> s_load)
    const float* __restrict__ bnFs,           // folded scale/shift
    const int* __restrict__ flag,
    unsigned short* __restrict__ outp)        // B,F1,C,T bf16
{
  __shared__ __align__(16) float xs[1096];    // t in [tb-35, tb+1059]
  int tid = threadIdx.x;
  int bc = blockIdx.y;                 // b*64+c
  int b = bc >> 6, c = bc & 63;
  int tb = blockIdx.x * 1024;
  int isf32 = *flag;
  int row = bc * T_;
  for (int s = tid; s < 1095; s += 256) {
    int t = tb - 35 + s;
    xs[s] = (t >= 0 && t < T_) ? ldin(x, row + t, isf32) : 0.0f;
  }
  __syncthreads();
  int t0 = tb + 4*tid;
  if (t0 >= T_) return;
  float acc[8][4];
  #pragma unroll
  for (int f = 0; f < 8; ++f)
    #pragma unroll
    for (int j = 0; j < 4; ++j) acc[f][j] = 0.0f;
  // chunk cc handles taps k=4cc..4cc+3; input t0+j+k-31 = element 4tid+4+4cc+(k-4cc)+j
  float4 A4 = *(const float4*)(xs + 4*tid + 4);
  float4 B4 = *(const float4*)(xs + 4*tid + 8);
  for (int cc = 0; cc < 16; ++cc) {
    float ev[7] = {A4.x, A4.y, A4.z, A4.w, B4.x, B4.y, B4.z};
    #pragma unroll
    for (int kk = 0; kk < 4; ++kk) {
      #pragma unroll
      for (int f = 0; f < 8; ++f) {
        float wv = w1c[f*64 + 4*cc + kk];    // uniform -> SGPR
        #pragma unroll
        for (int j = 0; j < 4; ++j) acc[f][j] = fmaf(wv, ev[kk + j], acc[f][j]);
      }
    }
    A4 = B4;
    if (cc < 15) B4 = *(const float4*)(xs + 4*tid + 12 + 4*cc);  // next B-half
  }
  #pragma unroll
  for (int f = 0; f < 8; ++f) {
    float sc = bnFs[f], sh = bnFs[8 + f];
    ushort4 v;
    v.x = f2bf(acc[f][0]*sc + sh);
    v.y = f2bf(acc[f][1]*sc + sh);
    v.z = f2bf(acc[f][2]*sc + sh);
    v.w = f2bf(acc[f][3]*sc + sh);
    *(ushort4*)(outp + ((b*8 + f)*64 + c)*T_ + t0) = v;
  }
}

// ---------------- K2: sparse graph einsum, packed 2 t/thread ---------------
// grid (8 t-tiles of 512, B*F1). 64 rows x 256 uints (2 bf16) in LDS.
__global__ __launch_bounds__(256) void k2_gcn(
    const unsigned short* __restrict__ in,    // B,F1,C,T bf16
    unsigned short* __restrict__ outp,        // B,F1,C,T bf16
    const int* __restrict__ deg, const int* __restrict__ col,
    const float* __restrict__ avals, int l)
{
  __shared__ unsigned int sl[64*256];
  int tid = threadIdx.x;
  int bf = blockIdx.y;                 // b*8+f
  int tb = blockIdx.x * 512;
  int base = bf * (64 * T_);
  for (int idx = tid; idx < 64*256; idx += 256) {
    int d = idx >> 8, u = idx & 255;
    int t = tb + 2*u;
    unsigned int v = 0;
    if (t + 1 < T_) v = *(const unsigned int*)(in + base + d*T_ + t);
    sl[idx] = v;
  }
  __syncthreads();
  int t0 = tb + 2*tid;
  if (t0 >= T_) return;
  int f = bf & 7;
  const float* av = avals + (l*8 + f) * (64 * MAXDEG);
  for (int c = 0; c < 64; ++c) {
    int dg = deg[c];                   // uniform -> s_load
    float a0 = 0.0f, a1 = 0.0f;
    for (int e = 0; e < dg; ++e) {
      int d = col[c*MAXDEG + e];       // uniform
      float wv = av[c*MAXDEG + e];     // uniform
      unsigned int v = sl[(d << 8) + tid];
      a0 = fmaf(wv, lo_f(v), a0);
      a1 = fmaf(wv, hi_f(v), a1);
    }
    unsigned int o = ((unsigned int)f2bf(a1) << 16) | (unsigned int)f2bf(a0);
    *(unsigned int*)(outp + base + c*T_ + t0) = o;
  }
}

// ---------------- K3: gconv (8ch x 8tap) + bn + elu. 4 t/thread ------------
// grid (4 t-tiles of 1024, B*C). Rows staged from t=tb-4 (aligned reads).
__global__ __launch_bounds__(256, 4) void k3_gconv(
    const unsigned short* __restrict__ in,    // B,F1,C,T bf16 (Ah)
    const float* __restrict__ gwc,            // 3x8x8x8 fp32 (uniform)
    const float* __restrict__ bnFs,
    unsigned short* __restrict__ outp,        // B,F1,C,T bf16
    int l)
{
  __shared__ __align__(16) float xsh[8*1040]; // 8 rows, t in [tb-4, tb+1027]
  int tid = threadIdx.x;
  int bc = blockIdx.y;                 // b*64+c
  int b = bc >> 6, c = bc & 63;
  int tb = blockIdx.x * 1024;
  for (int i = 0; i < 8; ++i) {
    int rb = ((b*8 + i)*64 + c) * T_;
    for (int u = tid; u < 516; u += 256) {
      int s = 2*u;                     // element pair within row
      int t = tb - 4 + s;
      float f0 = 0.0f, f1 = 0.0f;
      if (t >= 0 && t + 1 < T_) {
        unsigned int v = *(const unsigned int*)(in + rb + t);
        f0 = lo_f(v); f1 = hi_f(v);
      } else {
        if (t >= 0 && t < T_)     f0 = bf2f(in[rb + t]);
        if (t+1 >= 0 && t+1 < T_) f1 = bf2f(in[rb + t + 1]);
      }
      if (s < 1032)   xsh[i*1040 + s] = f0;
      if (s+1 < 1032) xsh[i*1040 + s + 1] = f1;
    }
  }
  __syncthreads();
  int t0 = tb + 4*tid;
  if (t0 >= T_) return;
  float acc[8][4];
  #pragma unroll
  for (int o = 0; o < 8; ++o)
    #pragma unroll
    for (int j = 0; j < 4; ++j) acc[o][j] = 0.0f;
  const float* gl = gwc + l*512;
  for (int i = 0; i < 8; ++i) {
    const float* row = xsh + i*1040;
    float4 A4 = *(const float4*)(row + 4*tid);      // t0-4 .. t0-1
    float4 B4 = *(const float4*)(row + 4*tid + 4);  // t0   .. t0+3
    float4 C4 = *(const float4*)(row + 4*tid + 8);  // t0+4 .. t0+7
    float ev[12] = {A4.x, A4.y, A4.z, A4.w, B4.x, B4.y, B4.z, B4.w,
                    C4.x, C4.y, C4.z, C4.w};
    #pragma unroll
    for (int k = 0; k < 8; ++k) {
      #pragma unroll
      for (int o = 0; o < 8; ++o) {
        float wv = gl[(o*8 + i)*8 + k];  // uniform -> SGPR
        #pragma unroll
        for (int j = 0; j < 4; ++j)
          acc[o][j] = fmaf(wv, ev[j + k + 1], acc[o][j]);  // in t = t0+j+k-3
      }
    }
  }
  #pragma unroll
  for (int o = 0; o < 8; ++o) {
    float sc = bnFs[(l+1)*16 + o], sh = bnFs[(l+1)*16 + 8 + o];
    ushort4 v;
    v.x = f2bf(eluf(acc[o][0]*sc + sh));
    v.y = f2bf(eluf(acc[o][1]*sc + sh));
    v.z = f2bf(eluf(acc[o][2]*sc + sh));
    v.w = f2bf(eluf(acc[o][3]*sc + sh));
    *(ushort4*)(outp + ((b*8 + o)*64 + c)*T_ + t0) = v;
  }
}

// ---------------- K4: depthwise-over-C + bn + elu + avgpool4, 2 t/thread ---
__global__ __launch_bounds__(256) void k4_dw(
    const unsigned short* __restrict__ in,    // B,F1,C,T bf16
    const float* __restrict__ dwn,            // 16x64 (uniform)
    const float* __restrict__ bnsps,
    float* __restrict__ p1)                   // B,16,1000 fp32
{
  __shared__ unsigned int sl[64*256];
  __shared__ float es[2][512];
  int tid = threadIdx.x;
  int bg = blockIdx.y;                 // b*8+g
  int b = bg >> 3, g = bg & 7;
  int tb = blockIdx.x * 512;
  int base = bg * (64 * T_);
  for (int idx = tid; idx < 64*256; idx += 256) {
    int cc = idx >> 8, u = idx & 255;
    int t = tb + 2*u;
    unsigned int v = 0;
    if (t + 1 < T_) v = *(const unsigned int*)(in + base + cc*T_ + t);
    sl[idx] = v;
  }
  __syncthreads();
  int t0 = tb + 2*tid;
  if (t0 < T_) {
    float a00 = 0.0f, a01 = 0.0f, a10 = 0.0f, a11 = 0.0f;
    for (int cc = 0; cc < 64; ++cc) {
      float w0 = dwn[(2*g)*64 + cc];     // uniform
      float w1 = dwn[(2*g+1)*64 + cc];   // uniform
      unsigned int v = sl[(cc << 8) + tid];
      float h0 = lo_f(v), h1 = hi_f(v);
      a00 = fmaf(w0, h0, a00); a01 = fmaf(w0, h1, a01);
      a10 = fmaf(w1, h0, a10); a11 = fmaf(w1, h1, a11);
    }
    float sc0 = bnsps[2*g],     sh0 = bnsps[16 + 2*g];
    float sc1 = bnsps[2*g + 1], sh1 = bnsps[16 + 2*g + 1];
    es[0][2*tid]     = eluf(a00*sc0 + sh0);
    es[0][2*tid + 1] = eluf(a01*sc0 + sh0);
    es[1][2*tid]     = eluf(a10*sc1 + sh1);
    es[1][2*tid + 1] = eluf(a11*sc1 + sh1);
  }
  __syncthreads();
  {
    int j = tid >> 7, q = tid & 127;
    int oi = (tb >> 2) + q;
    if (oi < TP_) {
      float s = es[j][4*q] + es[j][4*q+1] + es[j][4*q+2] + es[j][4*q+3];
      p1[(b*16 + 2*g + j)*TP_ + oi] = 0.25f * s;
    }
  }
}

// ---------------- K5: sep depthwise(16) + pointwise(16x16) + bn + elu ------
// grid (4 w-tiles of 256, B).
__global__ __launch_bounds__(256) void k5_sep(
    const float* __restrict__ p1,             // B,16,1000
    const float* __restrict__ sdwc,           // 16x16 (uniform)
    const float* __restrict__ pwc,            // 16x16 (uniform)
    const float* __restrict__ bnseps,
    float* __restrict__ p2)                   // B,16,1001
{
  __shared__ float ps[16*272];
  int tid = threadIdx.x;
  int wq = blockIdx.x, b = blockIdx.y;
  int wb = wq * 256;
  for (int ch = 0; ch < 16; ++ch) {
    for (int s = tid; s < 272; s += 256) {
      int t = wb - 8 + s;
      ps[ch*272 + s] = (t >= 0 && t < TP_) ? p1[(b*16 + ch)*TP_ + t] : 0.0f;
    }
  }
  __syncthreads();
  int w0 = wb + tid;
  if (w0 >= W2_) return;
  float dws[16];
  for (int ch = 0; ch < 16; ++ch) {
    float a = 0.0f;
    #pragma unroll
    for (int k = 0; k < 16; ++k)
      a = fmaf(sdwc[ch*16 + k], ps[ch*272 + tid + k], a);
    dws[ch] = a;
  }
  for (int f = 0; f < 16; ++f) {
    float a = 0.0f;
    #pragma unroll
    for (int ch = 0; ch < 16; ++ch) a = fmaf(pwc[f*16 + ch], dws[ch], a);
    float sc = bnseps[f], sh = bnseps[16 + f];
    p2[(b*16 + f)*W2_ + w0] = eluf(a*sc + sh);
  }
}

// ---------------- K6: avgpool8 (first 1000) + fc ---------------------------
__global__ __launch_bounds__(256) void k6_fc(
    const float* __restrict__ p2,             // B,16,1001
    const float* __restrict__ fcwc,           // 4x2000
    const float* __restrict__ fcbc,           // 4
    const int* __restrict__ flag,
    void* __restrict__ outp)                  // B,4
{
  __shared__ float red[4*256];
  int tid = threadIdx.x;
  int b = blockIdx.x;
  float part[4] = {0.0f, 0.0f, 0.0f, 0.0f};
  for (int idx = tid; idx < 2000; idx += 256) {
    int f = idx / 125, q = idx - f*125;
    const float* src = p2 + (b*16 + f)*W2_ + q*8;
    float s = src[0]+src[1]+src[2]+src[3]+src[4]+src[5]+src[6]+src[7];
    float mval = 0.125f * s;
    #pragma unroll
    for (int n = 0; n < 4; ++n) part[n] = fmaf(fcwc[n*2000 + idx], mval, part[n]);
  }
  #pragma unroll
  for (int n = 0; n < 4; ++n) red[n*256 + tid] = part[n];
  __syncthreads();
  for (int s = 128; s > 0; s >>= 1) {
    if (tid < s) {
      #pragma unroll
      for (int n = 0; n < 4; ++n) red[n*256 + tid] += red[n*256 + tid + s];
    }
    __syncthreads();
  }
  if (tid < 4) {
    float val = red[tid*256] + fcbc[tid];
    if (*flag) ((float*)outp)[b*4 + tid] = val;
    else       ((unsigned short*)outp)[b*4 + tid] = f2bf(val);
  }
}

// ---------------------------------------------------------------------------
extern "C" void kernel_launch(void* const* d_in, const int* in_sizes, int n_in,
                              void* d_out, int out_size, void* d_ws, size_t ws_size,
                              hipStream_t stream) {
  const void* x     = d_in[0];
  const void* adj   = d_in[1];
  const void* w1    = d_in[2];
  const void* bnF   = d_in[3];
  const void* imp   = d_in[4];
  const void* gw    = d_in[5];
  const void* dww   = d_in[6];
  const void* bnsp  = d_in[7];
  const void* sdw   = d_in[8];
  const void* pw    = d_in[9];
  const void* bnsep = d_in[10];
  const void* fcw   = d_in[11];
  const void* fcb   = d_in[12];

  char* w = (char*)d_ws;
  const size_t OFF = 262144000;  // after two 131,072,000-byte bf16 buffers
  unsigned short* bufA = (unsigned short*)(w);
  unsigned short* bufB = (unsigned short*)(w + 131072000);
  int*   flag   = (int*)  (w + OFF + 0);
  int*   deg    = (int*)  (w + OFF + 256);
  int*   col    = (int*)  (w + OFF + 512);
  float* avals  = (float*)(w + OFF + 4608);
  float* w1c    = (float*)(w + OFF + 102912);
  float* gwc    = (float*)(w + OFF + 104960);
  float* dwn    = (float*)(w + OFF + 111104);
  float* sdwc   = (float*)(w + OFF + 115200);
  float* pwc    = (float*)(w + OFF + 116224);
  float* fcwc   = (float*)(w + OFF + 117248);
  float* fcbc   = (float*)(w + OFF + 149248);
  float* bnFs   = (float*)(w + OFF + 149504);
  float* bnsps  = (float*)(w + OFF + 149760);
  float* bnseps = (float*)(w + OFF + 150016);
  float* p1     = (float*)(w + OFF + 150272);
  float* p2     = (float*)(w + OFF + 2198272);

  k0_setup<<<1, 256, 0, stream>>>(adj, imp, dww, w1, bnF, gw, bnsp, sdw, pw,
                                  bnsep, fcw, fcb, flag, deg, col, avals,
                                  w1c, gwc, dwn, sdwc, pwc, fcwc, fcbc,
                                  bnFs, bnsps, bnseps);
  k1_conv1_bn<<<dim3(4, B_*C_), 256, 0, stream>>>(x, w1c, bnFs, flag, bufA);
  for (int l = 0; l < 3; ++l) {
    k2_gcn<<<dim3(8, B_*F1_), 256, 0, stream>>>(bufA, bufB, deg, col, avals, l);
    k3_gconv<<<dim3(4, B_*C_), 256, 0, stream>>>(bufB, gwc, bnFs, bufA, l);
  }
  k4_dw<<<dim3(8, B_*F1_), 256, 0, stream>>>(bufA, dwn, bnsps, p1);
  k5_sep<<<dim3(4, B_), 256, 0, stream>>>(p1, sdwc, pwc, bnseps, p2);
  k6_fc<<<32, 256, 0, stream>>>(p2, fcwc, fcbc, flag, d_out);
}

// Round 5
// 946.257 us; speedup vs baseline: 4.0665x; 1.5680x over previous
//
#include <hip/hip_runtime.h>

// GCN-EEGNet forward, MI355X. Dtype-adaptive (fp32/bf16 inputs detected in
// K0 via adjacency sentinel). Weights fp32 in ws, read with WAVE-UNIFORM
// indices -> SGPR operands. Big intermediates bf16 in ws (bufA/bufB).
// Round-5: k2/k3/k4 are LDS-FREE — per-thread aligned uint2 (4xbf16) global
// loads, L1/L2 absorb window overlap; occupancy VGPR-bound (round-4 showed
// 64KB-LDS staging capped k2/k4 at 2 blocks/CU, 872 GB/s, latency-bound).
// Pipeline: K0 setup -> K1 conv1+bn -> 3x [K2 sparse graph einsum ->
// K3 gconv+bn+elu] -> K4 dw+bn+elu+pool4 -> K5 sep(dw+pw)+bn+elu -> K6 fc.

#define B_   32
#define C_   64
#define T_   4000
#define F1_  8
#define TP_  1000
#define W2_  1001
#define MAXDEG 16

static __device__ __forceinline__ float bf2f(unsigned short h) {
  union { unsigned int u; float f; } v; v.u = ((unsigned int)h) << 16; return v.f;
}
static __device__ __forceinline__ float lo_f(unsigned int u) {
  union { unsigned int u; float f; } v; v.u = u << 16; return v.f;
}
static __device__ __forceinline__ float hi_f(unsigned int u) {
  union { unsigned int u; float f; } v; v.u = u & 0xFFFF0000u; return v.f;
}
static __device__ __forceinline__ unsigned short f2bf(float f) {
  union { float f; unsigned int u; } v; v.f = f;
  unsigned int r = v.u + 0x7FFFu + ((v.u >> 16) & 1u);
  return (unsigned short)(r >> 16);
}
static __device__ __forceinline__ unsigned int pack2(float a, float b) {
  return ((unsigned int)f2bf(b) << 16) | (unsigned int)f2bf(a);
}
static __device__ __forceinline__ float eluf(float z) {
  return z > 0.0f ? z : expm1f(z);
}
static __device__ __forceinline__ float ldin(const void* p, int i, int isf32) {
  return isf32 ? ((const float*)p)[i] : bf2f(((const unsigned short*)p)[i]);
}

// ---------------- K0: dtype detect + canonicalize + CSR + bn fold ----------
__global__ __launch_bounds__(256) void k0_setup(
    const void* __restrict__ adj, const void* __restrict__ imp,
    const void* __restrict__ dww, const void* __restrict__ w1,
    const void* __restrict__ bnF, const void* __restrict__ gw,
    const void* __restrict__ bnsp, const void* __restrict__ sdw,
    const void* __restrict__ pw, const void* __restrict__ bnsep,
    const void* __restrict__ fcw, const void* __restrict__ fcb,
    int* __restrict__ flag, int* __restrict__ deg, int* __restrict__ col,
    float* __restrict__ avals, float* __restrict__ w1c,
    float* __restrict__ gwc, float* __restrict__ dwn,
    float* __restrict__ sdwc, float* __restrict__ pwc,
    float* __restrict__ fcwc, float* __restrict__ fcbc,
    float* __restrict__ bnFs, float* __restrict__ bnsps,
    float* __restrict__ bnseps)
{
  __shared__ float dwr[1024];
  __shared__ float dsc[16];
  int tid = threadIdx.x;
  int isf32 = (((const float*)adj)[0] == 1.0f) ? 1 : 0;
  if (tid == 0) *flag = isf32;

  for (int i = tid; i < 512;  i += 256) w1c[i]  = ldin(w1, i, isf32);
  for (int i = tid; i < 1536; i += 256) gwc[i]  = ldin(gw, i, isf32);
  for (int i = tid; i < 256;  i += 256) sdwc[i] = ldin(sdw, i, isf32);
  for (int i = tid; i < 256;  i += 256) pwc[i]  = ldin(pw, i, isf32);
  for (int i = tid; i < 8000; i += 256) fcwc[i] = ldin(fcw, i, isf32);
  if (tid < 4) fcbc[tid] = ldin(fcb, tid, isf32);
  for (int i = tid; i < 1024; i += 256) dwr[i] = ldin(dww, i, isf32);

  if (tid < 64) {            // CSR of adjacency (data-driven)
    int c = tid, n = 0;
    for (int d = 0; d < 64; ++d) {
      if (ldin(adj, c*64 + d, isf32) != 0.0f) {
        if (n < MAXDEG) col[c*MAXDEG + n] = d;
        ++n;
      }
    }
    deg[c] = n < MAXDEG ? n : MAXDEG;
  }
  __syncthreads();
  if (tid < 16) {            // dw norm clamp scale
    float s2 = 0.0f;
    for (int c2 = 0; c2 < 64; ++c2) { float wv = dwr[tid*64 + c2]; s2 += wv*wv; }
    dsc[tid] = fminf(1.0f, 1.0f / fmaxf(sqrtf(s2), 1e-7f));
  }
  if (tid >= 64 && tid < 96) {   // bnF folded scale/shift: 4 stages x 8 ch
    int i = tid - 64, s = i >> 3, f = i & 7;
    float g = ldin(bnF, s*32 + f,      isf32);
    float b = ldin(bnF, s*32 + 8 + f,  isf32);
    float m = ldin(bnF, s*32 + 16 + f, isf32);
    float v = ldin(bnF, s*32 + 24 + f, isf32);
    float sc = g * rsqrtf(v + 1e-3f);
    bnFs[s*16 + f] = sc; bnFs[s*16 + 8 + f] = b - m*sc;
  }
  if (tid >= 96 && tid < 112) {  // bn_sp
    int ch = tid - 96;
    float g = ldin(bnsp, ch, isf32), b = ldin(bnsp, 16 + ch, isf32);
    float m = ldin(bnsp, 32 + ch, isf32), v = ldin(bnsp, 48 + ch, isf32);
    float sc = g * rsqrtf(v + 1e-3f);
    bnsps[ch] = sc; bnsps[16 + ch] = b - m*sc;
  }
  if (tid >= 112 && tid < 128) { // bn_sep
    int ch = tid - 112;
    float g = ldin(bnsep, ch, isf32), b = ldin(bnsep, 16 + ch, isf32);
    float m = ldin(bnsep, 32 + ch, isf32), v = ldin(bnsep, 48 + ch, isf32);
    float sc = g * rsqrtf(v + 1e-3f);
    bnseps[ch] = sc; bnseps[16 + ch] = b - m*sc;
  }
  for (int combo = tid; combo < 3*8*64; combo += 256) {
    int l = combo >> 9, f = (combo >> 6) & 7, c = combo & 63;
    int dg = deg[c];
    for (int e = 0; e < dg; ++e) {
      int d = col[c*MAXDEG + e];
      avals[((l*8 + f)*64 + c)*MAXDEG + e] =
          ldin(adj, c*64 + d, isf32) * ldin(imp, ((l*8 + f)*64 + c)*64 + d, isf32);
    }
  }
  __syncthreads();
  for (int i = tid; i < 1024; i += 256) dwn[i] = dwr[i] * dsc[i >> 6];
}

// ---------------- K1: conv1 (64-tap) + bn0. 4 t/thread, SGPR weights -------
// grid (4 t-tiles of 1024, B*C). Stage row from t=tb-35 so float4 reads align.
// Invariant entering chunk cc: A4 = xs[4tid+4+4cc ..], B4 = xs[4tid+8+4cc ..].
__global__ __launch_bounds__(256, 4) void k1_conv1_bn(
    const void* __restrict__ x,               // B,C,T raw dtype
    const float* __restrict__ w1c,            // 8x64 fp32 (uniform -> s_load)
    const float* __restrict__ bnFs,           // folded scale/shift
    const int* __restrict__ flag,
    unsigned short* __restrict__ outp)        // B,F1,C,T bf16
{
  __shared__ __align__(16) float xs[1096];    // t in [tb-35, tb+1059]
  int tid = threadIdx.x;
  int bc = blockIdx.y;                 // b*64+c
  int b = bc >> 6, c = bc & 63;
  int tb = blockIdx.x * 1024;
  int isf32 = *flag;
  int row = bc * T_;
  for (int s = tid; s < 1095; s += 256) {
    int t = tb - 35 + s;
    xs[s] = (t >= 0 && t < T_) ? ldin(x, row + t, isf32) : 0.0f;
  }
  __syncthreads();
  int t0 = tb + 4*tid;
  if (t0 >= T_) return;
  float acc[8][4];
  #pragma unroll
  for (int f = 0; f < 8; ++f)
    #pragma unroll
    for (int j = 0; j < 4; ++j) acc[f][j] = 0.0f;
  // chunk cc handles taps k=4cc..4cc+3; input t0+j+k-31 = element 4tid+4+4cc+(k-4cc)+j
  float4 A4 = *(const float4*)(xs + 4*tid + 4);
  float4 B4 = *(const float4*)(xs + 4*tid + 8);
  for (int cc = 0; cc < 16; ++cc) {
    float ev[7] = {A4.x, A4.y, A4.z, A4.w, B4.x, B4.y, B4.z};
    #pragma unroll
    for (int kk = 0; kk < 4; ++kk) {
      #pragma unroll
      for (int f = 0; f < 8; ++f) {
        float wv = w1c[f*64 + 4*cc + kk];    // uniform -> SGPR
        #pragma unroll
        for (int j = 0; j < 4; ++j) acc[f][j] = fmaf(wv, ev[kk + j], acc[f][j]);
      }
    }
    A4 = B4;
    if (cc < 15) B4 = *(const float4*)(xs + 4*tid + 12 + 4*cc);  // next B-half
  }
  #pragma unroll
  for (int f = 0; f < 8; ++f) {
    float sc = bnFs[f], sh = bnFs[8 + f];
    ushort4 v;
    v.x = f2bf(acc[f][0]*sc + sh);
    v.y = f2bf(acc[f][1]*sc + sh);
    v.z = f2bf(acc[f][2]*sc + sh);
    v.w = f2bf(acc[f][3]*sc + sh);
    *(ushort4*)(outp + ((b*8 + f)*64 + c)*T_ + t0) = v;
  }
}

// ---------------- K2: sparse graph einsum, LDS-free, 4 t/thread ------------
// grid (4 t-tiles of 1024, B*F1). Direct aligned uint2 loads; rows re-hit in
// L1/L2 across the c-loop (Sum deg ~252 loads/thread, all independent).
__global__ __launch_bounds__(256) void k2_gcn(
    const unsigned short* __restrict__ in,    // B,F1,C,T bf16
    unsigned short* __restrict__ outp,        // B,F1,C,T bf16
    const int* __restrict__ deg, const int* __restrict__ col,
    const float* __restrict__ avals, int l)
{
  int tid = threadIdx.x;
  int bf = blockIdx.y;                 // b*8+f
  int t0 = blockIdx.x * 1024 + 4*tid;
  if (t0 >= T_) return;
  int base = bf * (64 * T_);
  int f = bf & 7;
  const float* av = avals + (l*8 + f) * (64 * MAXDEG);
  for (int c = 0; c < 64; ++c) {
    int dg = deg[c];                   // uniform -> s_load
    float a0 = 0.0f, a1 = 0.0f, a2 = 0.0f, a3 = 0.0f;
    for (int e = 0; e < dg; ++e) {
      int d = col[c*MAXDEG + e];       // uniform
      float wv = av[c*MAXDEG + e];     // uniform
      uint2 v = *(const uint2*)(in + base + d*T_ + t0);
      a0 = fmaf(wv, lo_f(v.x), a0); a1 = fmaf(wv, hi_f(v.x), a1);
      a2 = fmaf(wv, lo_f(v.y), a2); a3 = fmaf(wv, hi_f(v.y), a3);
    }
    uint2 o; o.x = pack2(a0, a1); o.y = pack2(a2, a3);
    *(uint2*)(outp + base + c*T_ + t0) = o;
  }
}

// ---------------- K3: gconv (8ch x 8tap) + bn + elu. LDS-free, 4 t/thread --
// grid (4 t-tiles of 1024, B*C). Window [t0-4,t0+8) via 3 aligned uint2;
// adjacent lanes overlap -> L1 hits. Edge lanes (t0==0, t0>=3993) take a
// guarded scalar path (only first/last x-tile has any).
__global__ __launch_bounds__(256) void k3_gconv(
    const unsigned short* __restrict__ in,    // B,F1,C,T bf16 (Ah)
    const float* __restrict__ gwc,            // 3x8x8x8 fp32 (uniform)
    const float* __restrict__ bnFs,
    unsigned short* __restrict__ outp,        // B,F1,C,T bf16
    int l)
{
  int tid = threadIdx.x;
  int bc = blockIdx.y;                 // b*64+c
  int b = bc >> 6, c = bc & 63;
  int t0 = blockIdx.x * 1024 + 4*tid;
  if (t0 >= T_) return;
  bool edge = (t0 == 0) || (t0 + 7 >= T_);   // window [t0-3, t0+7]
  float acc[8][4];
  #pragma unroll
  for (int o = 0; o < 8; ++o)
    #pragma unroll
    for (int j = 0; j < 4; ++j) acc[o][j] = 0.0f;
  const float* gl = gwc + l*512;
  for (int i = 0; i < 8; ++i) {
    int row = ((b*8 + i)*64 + c) * T_;
    float ev[12];                      // ev[s] ~ t = t0-4+s
    if (!edge) {
      const unsigned short* rp = in + row + t0 - 4;
      uint2 u0 = *(const uint2*)(rp);
      uint2 u1 = *(const uint2*)(rp + 4);
      uint2 u2 = *(const uint2*)(rp + 8);
      ev[0] = lo_f(u0.x); ev[1] = hi_f(u0.x); ev[2] = lo_f(u0.y); ev[3] = hi_f(u0.y);
      ev[4] = lo_f(u1.x); ev[5] = hi_f(u1.x); ev[6] = lo_f(u1.y); ev[7] = hi_f(u1.y);
      ev[8] = lo_f(u2.x); ev[9] = hi_f(u2.x); ev[10]= lo_f(u2.y); ev[11]= hi_f(u2.y);
    } else {
      #pragma unroll
      for (int s = 0; s < 12; ++s) {
        int t = t0 - 4 + s;
        ev[s] = (t >= 0 && t < T_) ? bf2f(in[row + t]) : 0.0f;
      }
    }
    #pragma unroll
    for (int k = 0; k < 8; ++k) {
      #pragma unroll
      for (int o = 0; o < 8; ++o) {
        float wv = gl[(o*8 + i)*8 + k];  // uniform -> SGPR
        #pragma unroll
        for (int j = 0; j < 4; ++j)
          acc[o][j] = fmaf(wv, ev[j + k + 1], acc[o][j]);  // in t = t0+j+k-3
      }
    }
  }
  #pragma unroll
  for (int o = 0; o < 8; ++o) {
    float sc = bnFs[(l+1)*16 + o], sh = bnFs[(l+1)*16 + 8 + o];
    ushort4 v;
    v.x = f2bf(eluf(acc[o][0]*sc + sh));
    v.y = f2bf(eluf(acc[o][1]*sc + sh));
    v.z = f2bf(eluf(acc[o][2]*sc + sh));
    v.w = f2bf(eluf(acc[o][3]*sc + sh));
    *(ushort4*)(outp + ((b*8 + o)*64 + c)*T_ + t0) = v;
  }
}

// ---------------- K4: depthwise-over-C + bn + elu + avgpool4. LDS-free -----
// grid (4 t-tiles of 1024, B*F1). 4 t/thread == one pool window exactly.
__global__ __launch_bounds__(256) void k4_dw(
    const unsigned short* __restrict__ in,    // B,F1,C,T bf16
    const float* __restrict__ dwn,            // 16x64 (uniform)
    const float* __restrict__ bnsps,
    float* __restrict__ p1)                   // B,16,1000 fp32
{
  int tid = threadIdx.x;
  int bg = blockIdx.y;                 // b*8+g
  int b = bg >> 3, g = bg & 7;
  int t0 = blockIdx.x * 1024 + 4*tid;
  if (t0 >= T_) return;
  int base = bg * (64 * T_);
  float a0[4] = {0,0,0,0}, a1[4] = {0,0,0,0};
  for (int cc = 0; cc < 64; ++cc) {
    float w0 = dwn[(2*g)*64 + cc];     // uniform
    float w1 = dwn[(2*g+1)*64 + cc];   // uniform
    uint2 v = *(const uint2*)(in + base + cc*T_ + t0);
    float h0 = lo_f(v.x), h1 = hi_f(v.x), h2 = lo_f(v.y), h3 = hi_f(v.y);
    a0[0] = fmaf(w0, h0, a0[0]); a0[1] = fmaf(w0, h1, a0[1]);
    a0[2] = fmaf(w0, h2, a0[2]); a0[3] = fmaf(w0, h3, a0[3]);
    a1[0] = fmaf(w1, h0, a1[0]); a1[1] = fmaf(w1, h1, a1[1]);
    a1[2] = fmaf(w1, h2, a1[2]); a1[3] = fmaf(w1, h3, a1[3]);
  }
  float sc0 = bnsps[2*g],     sh0 = bnsps[16 + 2*g];
  float sc1 = bnsps[2*g + 1], sh1 = bnsps[16 + 2*g + 1];
  float s0 = eluf(a0[0]*sc0 + sh0) + eluf(a0[1]*sc0 + sh0)
           + eluf(a0[2]*sc0 + sh0) + eluf(a0[3]*sc0 + sh0);
  float s1 = eluf(a1[0]*sc1 + sh1) + eluf(a1[1]*sc1 + sh1)
           + eluf(a1[2]*sc1 + sh1) + eluf(a1[3]*sc1 + sh1);
  int oi = t0 >> 2;
  p1[(b*16 + 2*g)*TP_ + oi]     = 0.25f * s0;
  p1[(b*16 + 2*g + 1)*TP_ + oi] = 0.25f * s1;
}

// ---------------- K5: sep depthwise(16) + pointwise(16x16) + bn + elu ------
// grid (4 w-tiles of 256, B).
__global__ __launch_bounds__(256) void k5_sep(
    const float* __restrict__ p1,             // B,16,1000
    const float* __restrict__ sdwc,           // 16x16 (uniform)
    const float* __restrict__ pwc,            // 16x16 (uniform)
    const float* __restrict__ bnseps,
    float* __restrict__ p2)                   // B,16,1001
{
  __shared__ float ps[16*272];
  int tid = threadIdx.x;
  int wq = blockIdx.x, b = blockIdx.y;
  int wb = wq * 256;
  for (int ch = 0; ch < 16; ++ch) {
    for (int s = tid; s < 272; s += 256) {
      int t = wb - 8 + s;
      ps[ch*272 + s] = (t >= 0 && t < TP_) ? p1[(b*16 + ch)*TP_ + t] : 0.0f;
    }
  }
  __syncthreads();
  int w0 = wb + tid;
  if (w0 >= W2_) return;
  float dws[16];
  for (int ch = 0; ch < 16; ++ch) {
    float a = 0.0f;
    #pragma unroll
    for (int k = 0; k < 16; ++k)
      a = fmaf(sdwc[ch*16 + k], ps[ch*272 + tid + k], a);
    dws[ch] = a;
  }
  for (int f = 0; f < 16; ++f) {
    float a = 0.0f;
    #pragma unroll
    for (int ch = 0; ch < 16; ++ch) a = fmaf(pwc[f*16 + ch], dws[ch], a);
    float sc = bnseps[f], sh = bnseps[16 + f];
    p2[(b*16 + f)*W2_ + w0] = eluf(a*sc + sh);
  }
}

// ---------------- K6: avgpool8 (first 1000) + fc ---------------------------
__global__ __launch_bounds__(256) void k6_fc(
    const float* __restrict__ p2,             // B,16,1001
    const float* __restrict__ fcwc,           // 4x2000
    const float* __restrict__ fcbc,           // 4
    const int* __restrict__ flag,
    void* __restrict__ outp)                  // B,4
{
  __shared__ float red[4*256];
  int tid = threadIdx.x;
  int b = blockIdx.x;
  float part[4] = {0.0f, 0.0f, 0.0f, 0.0f};
  for (int idx = tid; idx < 2000; idx += 256) {
    int f = idx / 125, q = idx - f*125;
    const float* src = p2 + (b*16 + f)*W2_ + q*8;
    float s = src[0]+src[1]+src[2]+src[3]+src[4]+src[5]+src[6]+src[7];
    float mval = 0.125f * s;
    #pragma unroll
    for (int n = 0; n < 4; ++n) part[n] = fmaf(fcwc[n*2000 + idx], mval, part[n]);
  }
  #pragma unroll
  for (int n = 0; n < 4; ++n) red[n*256 + tid] = part[n];
  __syncthreads();
  for (int s = 128; s > 0; s >>= 1) {
    if (tid < s) {
      #pragma unroll
      for (int n = 0; n < 4; ++n) red[n*256 + tid] += red[n*256 + tid + s];
    }
    __syncthreads();
  }
  if (tid < 4) {
    float val = red[tid*256] + fcbc[tid];
    if (*flag) ((float*)outp)[b*4 + tid] = val;
    else       ((unsigned short*)outp)[b*4 + tid] = f2bf(val);
  }
}

// ---------------------------------------------------------------------------
extern "C" void kernel_launch(void* const* d_in, const int* in_sizes, int n_in,
                              void* d_out, int out_size, void* d_ws, size_t ws_size,
                              hipStream_t stream) {
  const void* x     = d_in[0];
  const void* adj   = d_in[1];
  const void* w1    = d_in[2];
  const void* bnF   = d_in[3];
  const void* imp   = d_in[4];
  const void* gw    = d_in[5];
  const void* dww   = d_in[6];
  const void* bnsp  = d_in[7];
  const void* sdw   = d_in[8];
  const void* pw    = d_in[9];
  const void* bnsep = d_in[10];
  const void* fcw   = d_in[11];
  const void* fcb   = d_in[12];

  char* w = (char*)d_ws;
  const size_t OFF = 262144000;  // after two 131,072,000-byte bf16 buffers
  unsigned short* bufA = (unsigned short*)(w);
  unsigned short* bufB = (unsigned short*)(w + 131072000);
  int*   flag   = (int*)  (w + OFF + 0);
  int*   deg    = (int*)  (w + OFF + 256);
  int*   col    = (int*)  (w + OFF + 512);
  float* avals  = (float*)(w + OFF + 4608);
  float* w1c    = (float*)(w + OFF + 102912);
  float* gwc    = (float*)(w + OFF + 104960);
  float* dwn    = (float*)(w + OFF + 111104);
  float* sdwc   = (float*)(w + OFF + 115200);
  float* pwc    = (float*)(w + OFF + 116224);
  float* fcwc   = (float*)(w + OFF + 117248);
  float* fcbc   = (float*)(w + OFF + 149248);
  float* bnFs   = (float*)(w + OFF + 149504);
  float* bnsps  = (float*)(w + OFF + 149760);
  float* bnseps = (float*)(w + OFF + 150016);
  float* p1     = (float*)(w + OFF + 150272);
  float* p2     = (float*)(w + OFF + 2198272);

  k0_setup<<<1, 256, 0, stream>>>(adj, imp, dww, w1, bnF, gw, bnsp, sdw, pw,
                                  bnsep, fcw, fcb, flag, deg, col, avals,
                                  w1c, gwc, dwn, sdwc, pwc, fcwc, fcbc,
                                  bnFs, bnsps, bnseps);
  k1_conv1_bn<<<dim3(4, B_*C_), 256, 0, stream>>>(x, w1c, bnFs, flag, bufA);
  for (int l = 0; l < 3; ++l) {
    k2_gcn<<<dim3(4, B_*F1_), 256, 0, stream>>>(bufA, bufB, deg, col, avals, l);
    k3_gconv<<<dim3(4, B_*C_), 256, 0, stream>>>(bufB, gwc, bnFs, bufA, l);
  }
  k4_dw<<<dim3(4, B_*F1_), 256, 0, stream>>>(bufA, dwn, bnsps, p1);
  k5_sep<<<dim3(4, B_), 256, 0, stream>>>(p1, sdwc, pwc, bnseps, p2);
  k6_fc<<<32, 256, 0, stream>>>(p2, fcwc, fcbc, flag, d_out);
}